// Round 11
// baseline (119.068 us; speedup 1.0000x reference)
//
#include <hip/hip_runtime.h>

#define LL    1024
#define NB    8
#define NT    256          // 4 waves per WG
#define KCH   32           // steps per chunk (one barrier per chunk)
#define SKEW  96           // intra-WG wave skew = 64 rows + KCH
#define SBMAX 1056         // last chunk start (covers local steps up to 1087)
#define NCH   43           // wave 3 last active chunk: (1056+288)/32 = 42
#define YTN   1536         // y-table entries (float2) per table
#define BROW  1160         // bndX row stride (floats)
#define BOFF  128          // col 0 of a boundary row at index BOFF
#define GBASE 64           // d_ws float offset of link regions
#define GSTR  1280         // per-link region stride (floats)
#define C10   14.426950408889634f        // 10*log2(e)
#define CLOG  (-0.069314718055994531f)   // -(ln2)/10
#define EPS3  1e-12f
#define C3EPS 3e-12f                     // 3*eps (addend for the /3-folded fma)
#define THIRD 0.3333333333333333f

// Soft-DTW in e-space (e = exp(-10*D)); 16 strips x 64 rows across 4 WGs/batch.
// Round 11: minimal-latency step. Table holds (fp/3, fn/3) so
//   e_new = fma(ec3, (up_del + E1) + upa, ec3*3eps),  ec3 = min(EN*fp3, EP*fn3).
// upa via ONE merged DPP: update_dpp(old=Bsh, src=E1, wave_shr:1, bc=false)
// (lane0 keeps Bsh[0] = B[r]); Bsh maintained by wave_ror:1 per step.
// Staging write is exec-masked to lane 63 only. R7 barrier skeleton.

#define YB4(k) ((((k) >> 3) & 1)                                               \
    ? (((((k) & 7) >> 1) == 0) ? Bv0 : ((((k) & 7) >> 1) == 1) ? Bv1           \
                               : ((((k) & 7) >> 1) == 2) ? Bv2 : Bv3)          \
    : (((((k) & 7) >> 1) == 0) ? Av0 : ((((k) & 7) >> 1) == 1) ? Av1           \
                               : ((((k) & 7) >> 1) == 2) ? Av2 : Av3))
#define FPE(k) (((k) & 1) ? YB4(k).z : YB4(k).x)
#define FNE(k) (((k) & 1) ? YB4(k).w : YB4(k).y)

// Cell (lane+1, j) at local step s = lane + j; entry ji = s - lane + 256.
#define STEP(r) do {                                                           \
    const float fp3_ = FPE(r);                                                 \
    const float fn3_ = FNE(r);                                                 \
    const float upa_ = __int_as_float(__builtin_amdgcn_update_dpp(             \
        __float_as_int(Bsh), __float_as_int(E1),                               \
        0x138, 0xf, 0xf, false));                  /* wave_shr:1, keep old */  \
    Bsh = __int_as_float(__builtin_amdgcn_update_dpp(                          \
        __float_as_int(Bsh), __float_as_int(Bsh),                              \
        0x13C, 0xf, 0xf, false));                  /* wave_ror:1 */            \
    const float ec3_ = fminf(EN0 * fp3_, EP0 * fn3_);                          \
    const float sum_ = (up_del + E1) + upa_;                                   \
    const float nva_ = fmaf(ec3_, sum_, ec3_ * C3EPS);                         \
    if (stage63) stp[(r)] = nva_;                                              \
    lsum = sum_;                                                               \
    E1 = nva_; up_del = upa_;                                                  \
  } while (0)

#define LD4(d0, d1, d2, d3, byteoff) do {                                      \
    const char* p_ = ytp + (byteoff);                                          \
    d0 = *(const float4*)(p_);                                                 \
    d1 = *(const float4*)(p_ + 16);                                            \
    d2 = *(const float4*)(p_ + 32);                                            \
    d3 = *(const float4*)(p_ + 48);                                            \
  } while (0)

__global__ __launch_bounds__(NT, 1) void dtw_kernel(const float* __restrict__ outp,
                                                    const float* __restrict__ tgtp,
                                                    float* __restrict__ wsf) {
  const int bb = blockIdx.x >> 2;      // batch
  const int wg = blockIdx.x & 3;       // quarter: rows 256*wg+1 .. 256*wg+256
  const int t = threadIdx.x;
  const int lane = t & 63;
  const int wvs = __builtin_amdgcn_readfirstlane(t >> 6);

  __shared__ float2 ytabA[YTN];       // (fp/3, fn/3) at slot ji        (even lanes)
  __shared__ float2 ytabB[YTN];       // (fp/3, fn/3) at slot ji - 1    (odd lanes)
  __shared__ float  bndX[5][BROW];    // 0-2: waves 0-2 boundaries; 3: zeros+seed; 4: wave-3 staging

  {
    float4* za = (float4*)&ytabA[0];
    for (int i = t; i < (YTN * 2) / 4; i += NT) za[i] = make_float4(0.f, 0.f, 0.f, 0.f);
    float4* zb2 = (float4*)&ytabB[0];
    for (int i = t; i < (YTN * 2) / 4; i += NT) zb2[i] = make_float4(0.f, 0.f, 0.f, 0.f);
    float4* zb = (float4*)&bndX[0][0];
    for (int i = t; i < (5 * BROW) / 4; i += NT) zb[i] = make_float4(0.f, 0.f, 0.f, 0.f);
  }
  __syncthreads();

  const float* xb = outp + (size_t)bb * LL * LL;
  const float* yb = tgtp + (size_t)bb * LL * LL;

  // my row: global row 256*wg + 64*wvs + lane + 1
  const float xd = xb[256 * wg + 64 * wvs + lane];
  const float EP0 = __builtin_amdgcn_exp2f( C10 * xd);
  const float EN0 = __builtin_amdgcn_exp2f(-C10 * xd);

  {
    const float4 yv = *(const float4*)(yb + 4 * t);
    const float yy[4] = {yv.x, yv.y, yv.z, yv.w};
#pragma unroll
    for (int q = 0; q < 4; ++q) {
      const int ji = (4 * t + 1 + q) + 256;          // j in [1,1024]
      const float2 v = make_float2(__builtin_amdgcn_exp2f( C10 * yy[q]) * THIRD,
                                   __builtin_amdgcn_exp2f(-C10 * yy[q]) * THIRD);
      ytabA[ji] = v;
      ytabB[ji - 1] = v;
    }
  }
  if (wg == 0 && t == 0) bndX[3][BOFF] = 1.0f;      // e[0,0] = 1 seed
  const float costL = (wg == 3 && t == NT - 1) ? fabsf(xd - yb[LL - 1]) : 0.f;
  __syncthreads();

  float E1 = 0.f, up_del = 0.f, lsum = 0.f;
  float4 Av0, Av1, Av2, Av3;
  float4 Bv0 = make_float4(0.f, 0.f, 0.f, 0.f), Bv1 = Bv0, Bv2 = Bv0, Bv3 = Bv0;
  Av0 = Bv0; Av1 = Bv0; Av2 = Bv0; Av3 = Bv0;
  const bool isL0 = (lane == 0);
  const int wprev = (wvs == 0) ? 3 : (wvs - 1);
  const int wwr   = (wvs == 3) ? 4 : wvs;
  const bool isProd = (wg < 3) && (wvs == 3);
  const bool isCons = (wg > 0) && (wvs == 0);
  const bool stage63 = (lane == 63) && ((wvs < 3) || (wg < 3));
  // per-lane y-table view: 16B-aligned for every lane via the dual table
  const char* ytp = (lane & 1) ? (const char*)ytabB : (const char*)ytabA;
  const int   loff = 8 * (((lane & 1) ? 255 : 256) - lane);

  float* gprod = wsf + GBASE + (bb * 3 + wg)     * GSTR + 128;  // valid when wg<3
  float* gcons = wsf + GBASE + (bb * 3 + wg - 1) * GSTR + 128;  // valid when wg>0

  float Bpre = 0.f;
  int*  pcurB = (int*)gcons;
  if (isCons) {
    // sentinel-fill our link region (robust to any initial / stale d_ws content)
    for (int c0 = lane; c0 <= LL; c0 += 64)
      __hip_atomic_store((int*)(gcons + c0), __float_as_int(-1.0f),
                         __ATOMIC_RELAXED, __HIP_MEMORY_SCOPE_AGENT);
    __threadfence();
  }

#pragma unroll 1
  for (int c = 0; c < NCH; ++c) {
    const int sb = KCH * c - SKEW * wvs;   // local step at r=0 (multiple of 32)

    if (sb >= 0 && sb <= SBMAX) {
      const int base0 = loff + 8 * sb;
      // boundary window for THIS chunk (staged by the previous iteration)
      float B;
      if (isCons) {
        if (sb == 0) {
          pcurB = (int*)(gcons + lane);
          Bpre = __int_as_float(__hip_atomic_load(pcurB, __ATOMIC_RELAXED,
                                                  __HIP_MEMORY_SCOPE_AGENT));
        }
        float bv = Bpre;
        if (isL0 && sb == 0) bv = 0.f;                 // col 0 border: e = 0
        while (__ballot(bv < 0.f) & 0xffffffffull) {   // lanes 0..31 must be valid
          __builtin_amdgcn_s_sleep(2);
          bv = __int_as_float(__hip_atomic_load(pcurB, __ATOMIC_RELAXED,
                                                __HIP_MEMORY_SCOPE_AGENT));
          if (isL0 && sb == 0) bv = 0.f;
        }
        B = bv;
      } else {
        int colp = sb + lane; colp = colp > LL ? LL : colp;
        B = bndX[wprev][colp + BOFF];
      }
      if (sb == 0) {                      // first active chunk: no prefetch cover
        LD4(Av0, Av1, Av2, Av3, base0);          // g0: entries 0..7
        LD4(Bv0, Bv1, Bv2, Bv3, base0 + 64);     // g1: entries 8..15
      }
      float Bsh = B;                      // lane 0 holds B[r] after r rotations
      float* stp = &bndX[wwr][sb + 65];   // staging: col sb+r-63 at index sb+65+r

      STEP(0); STEP(1); STEP(2); STEP(3); STEP(4); STEP(5); STEP(6); STEP(7);
      LD4(Av0, Av1, Av2, Av3, base0 + 128);      // g2: entries 16..23 (use r=16)
      STEP(8); STEP(9); STEP(10); STEP(11); STEP(12); STEP(13); STEP(14); STEP(15);
      LD4(Bv0, Bv1, Bv2, Bv3, base0 + 192);      // g3: entries 24..31 (use r=24)
      STEP(16); STEP(17); STEP(18); STEP(19); STEP(20); STEP(21); STEP(22); STEP(23);
      const bool nact = (sb + KCH <= SBMAX);
      if (nact) LD4(Av0, Av1, Av2, Av3, base0 + 256);   // next g0 (use next r=0)
      STEP(24); STEP(25); STEP(26); STEP(27); STEP(28); STEP(29); STEP(30); STEP(31);
      if (nact) {
        LD4(Bv0, Bv1, Bv2, Bv3, base0 + 320);           // next g1 (use next r=8)
        if (isCons) {                    // prefetch next boundary window
          int cn = sb + KCH + lane; cn = cn > LL ? LL : cn;
          pcurB = (int*)(gcons + cn);
          Bpre = __int_as_float(__hip_atomic_load(pcurB, __ATOMIC_RELAXED,
                                                  __HIP_MEMORY_SCOPE_AGENT));
        }
      }
      if (isProd) {                      // tail export: window [sb-95, sb-32]
        int ec = sb - 95 + lane;
        ec = ec < 0 ? 0 : (ec > LL ? LL : ec);
        __hip_atomic_store((int*)(gprod + ec), __float_as_int(bndX[4][ec + BOFF]),
                           __ATOMIC_RELAXED, __HIP_MEMORY_SCOPE_AGENT);
      }
    }
    __syncthreads();
  }

  if (isProd) {   // backstop: full boundary-row sweep (correctness safety net)
    for (int c0 = lane; c0 <= LL; c0 += 64)
      __hip_atomic_store((int*)(gprod + c0), __float_as_int(bndX[4][c0 + BOFF]),
                         __ATOMIC_RELAXED, __HIP_MEMORY_SCOPE_AGENT);
  }

  // final cell (1024,1024): WG3 wave 3 lane 63 at s = 1087 (chunk sb=1056, r=31)
  if (wg == 3 && t == NT - 1) {
    const float m = fmaf(lsum, THIRD, EPS3);
    wsf[bb] = costL + CLOG * __builtin_amdgcn_logf(m);
  }
}

__global__ void reduce_mean(const float* __restrict__ ws, float* __restrict__ out) {
  if (threadIdx.x == 0 && blockIdx.x == 0) {
    float s = 0.f;
    for (int i = 0; i < NB; ++i) s += ws[i];
    out[0] = s * (1.0f / NB);
  }
}

extern "C" void kernel_launch(void* const* d_in, const int* in_sizes, int n_in,
                              void* d_out, int out_size, void* d_ws, size_t ws_size,
                              hipStream_t stream) {
  const float* o  = (const float*)d_in[0];
  const float* tg = (const float*)d_in[1];
  float* ws  = (float*)d_ws;
  float* out = (float*)d_out;

  dtw_kernel<<<4 * NB, NT, 0, stream>>>(o, tg, ws);
  reduce_mean<<<1, 64, 0, stream>>>(ws, out);
}

// Round 12
// 110.132 us; speedup vs baseline: 1.0811x; 1.0811x over previous
//
#include <hip/hip_runtime.h>

#define LL    1024
#define NB    8
#define NT    512          // 8 waves per WG, 2 per SIMD
#define KCH   32           // steps per chunk (one barrier per chunk)
#define SKEW  96           // intra-WG wave skew = 64 rows + KCH
#define SBMAX 1056         // last chunk start (covers local steps up to 1087)
#define NCH   55           // wave 7 last active chunk: (1056+672)/32 = 54
#define YOFF  192          // y-table entry offset (accessed ji range [193,1343])
#define YTN   1160         // y-table entries (float2) per table
#define BROW  1096         // bndX row stride (floats)
#define BOFF  64           // col 0 of a boundary row at index BOFF
#define GBASE 64           // d_ws float offset of link regions
#define GSTR  1152         // per-batch link region stride (floats; 1025 used)
#define C10   14.426950408889634f        // 10*log2(e)
#define CLOG  (-0.069314718055994531f)   // -(ln2)/10
#define EPS3  1e-12f

// Soft-DTW in e-space (e = exp(-10*D)); 16 strips x 64 rows, 2 WGs x 8 waves.
// R12 = R7's proven per-cell/handoff machinery (bit-exact, 87.5us) reshaped:
// 8 waves/WG = 2 waves/SIMD (stall hiding), ONE inter-WG LLC link per batch
// (was 3), batch's WG pair co-XCD via blockIdx decode bb=blk&7, wg=blk>>3.

#define YB4(k) ((((k) >> 3) & 1)                                               \
    ? (((((k) & 7) >> 1) == 0) ? Bv0 : ((((k) & 7) >> 1) == 1) ? Bv1           \
                               : ((((k) & 7) >> 1) == 2) ? Bv2 : Bv3)          \
    : (((((k) & 7) >> 1) == 0) ? Av0 : ((((k) & 7) >> 1) == 1) ? Av1           \
                               : ((((k) & 7) >> 1) == 2) ? Av2 : Av3))
#define FPE(k) (((k) & 1) ? YB4(k).z : YB4(k).x)
#define FNE(k) (((k) & 1) ? YB4(k).w : YB4(k).y)

// Cell (lane+1, j) at local step s = lane + j; entry ji = s - lane + 256.
#define STEP(r) do {                                                           \
    const float fp_ = FPE(r);                                                  \
    const float fn_ = FNE(r);                                                  \
    const float dppv_ = __int_as_float(__builtin_amdgcn_update_dpp(            \
        0, __float_as_int(E1), 0x138, 0xf, 0xf, true)); /* wave_shr:1 */       \
    const float bvs_ = __int_as_float(                                         \
        __builtin_amdgcn_readlane(__float_as_int(B), (r)));                    \
    const float upa_ = isL0 ? bvs_ : dppv_;                                    \
    const float eca_ = fminf(EN0 * fp_, EP0 * fn_);                            \
    const float mma_ = fmaf(up_del + E1 + upa_, (1.f / 3.f), EPS3);            \
    const float nva_ = eca_ * mma_;                                            \
    wbase[(r)] = nva_;                                                         \
    E1 = nva_; up_del = upa_; lastmm = mma_;                                   \
  } while (0)

#define LD4(d0, d1, d2, d3, byteoff) do {                                      \
    const char* p_ = ytp + (byteoff);                                          \
    d0 = *(const float4*)(p_);                                                 \
    d1 = *(const float4*)(p_ + 16);                                            \
    d2 = *(const float4*)(p_ + 32);                                            \
    d3 = *(const float4*)(p_ + 48);                                            \
  } while (0)

__global__ __launch_bounds__(NT, 1) void dtw_kernel(const float* __restrict__ outp,
                                                    const float* __restrict__ tgtp,
                                                    float* __restrict__ wsf) {
  const int bb = blockIdx.x & 7;       // batch (WG pair 8 blocks apart -> same XCD)
  const int wg = blockIdx.x >> 3;      // 0 = rows 1..512, 1 = rows 513..1024
  const int t = threadIdx.x;
  const int lane = t & 63;
  const int wvs = __builtin_amdgcn_readfirstlane(t >> 6);

  __shared__ float2 ytabA[YTN];       // (fp,fn) at slot ji-YOFF        (even lanes)
  __shared__ float2 ytabB[YTN];       // (fp,fn) at slot ji-1-YOFF      (odd lanes)
  __shared__ float  bndX[9][BROW];    // 0-6: waves 0-6 staging; 7: zeros+seed; 8: wave-7 staging
  __shared__ float  dumpA[8][64];     // LDS sink for non-lane-63 staging writes

  {
    float4* za = (float4*)&ytabA[0];
    for (int i = t; i < (YTN * 2) / 4; i += NT) za[i] = make_float4(0.f, 0.f, 0.f, 0.f);
    float4* zb2 = (float4*)&ytabB[0];
    for (int i = t; i < (YTN * 2) / 4; i += NT) zb2[i] = make_float4(0.f, 0.f, 0.f, 0.f);
    float4* zb = (float4*)&bndX[0][0];
    for (int i = t; i < (9 * BROW) / 4; i += NT) zb[i] = make_float4(0.f, 0.f, 0.f, 0.f);
  }
  __syncthreads();

  const float* xb = outp + (size_t)bb * LL * LL;
  const float* yb = tgtp + (size_t)bb * LL * LL;

  // my row: global row 512*wg + 64*wvs + lane + 1
  const float xd = xb[512 * wg + 64 * wvs + lane];
  const float EP0 = __builtin_amdgcn_exp2f( C10 * xd);
  const float EN0 = __builtin_amdgcn_exp2f(-C10 * xd);

  if (t < 256) {
    const float4 yv = *(const float4*)(yb + 4 * t);
    const float yy[4] = {yv.x, yv.y, yv.z, yv.w};
#pragma unroll
    for (int q = 0; q < 4; ++q) {
      const int ji = (4 * t + 1 + q) + 256;          // j in [1,1024]
      const float2 v = make_float2(__builtin_amdgcn_exp2f( C10 * yy[q]),
                                   __builtin_amdgcn_exp2f(-C10 * yy[q]));
      ytabA[ji - YOFF]     = v;
      ytabB[ji - 1 - YOFF] = v;
    }
  }
  if (wg == 0 && t == 0) bndX[7][BOFF] = 1.0f;      // e[0,0] = 1 seed
  const float costL = (wg == 1 && t == NT - 1) ? fabsf(xd - yb[LL - 1]) : 0.f;
  __syncthreads();

  float E1 = 0.f, up_del = 0.f, lastmm = EPS3;
  float4 Av0, Av1, Av2, Av3;
  float4 Bv0 = make_float4(0.f, 0.f, 0.f, 0.f), Bv1 = Bv0, Bv2 = Bv0, Bv3 = Bv0;
  Av0 = Bv0; Av1 = Bv0; Av2 = Bv0; Av3 = Bv0;
  const bool isL0 = (lane == 0);
  const int wprev = (wvs == 0) ? 7 : (wvs - 1);
  const int wwr   = (wvs == 7) ? 8 : wvs;
  const bool isProd = (wg == 0) && (wvs == 7);
  const bool isCons = (wg == 1) && (wvs == 0);
  // per-lane y-table view: 16B-aligned for every lane via the dual table
  const char* ytp = (lane & 1) ? (const char*)ytabB : (const char*)ytabA;
  const int   loff = 8 * (((lane & 1) ? 63 : 64) - lane);   // YOFF folded in

  float* glnk = wsf + GBASE + bb * GSTR;           // link cols 0..1024

  float Bpre = 0.f;
  int*  pcurB = (int*)glnk;
  if (isCons) {
    // sentinel-fill our link region (robust to any initial / stale d_ws content)
    for (int c0 = lane; c0 <= LL; c0 += 64)
      __hip_atomic_store((int*)(glnk + c0), __float_as_int(-1.0f),
                         __ATOMIC_RELAXED, __HIP_MEMORY_SCOPE_AGENT);
    __threadfence();
  }

#pragma unroll 1
  for (int c = 0; c < NCH; ++c) {
    const int sb = KCH * c - SKEW * wvs;   // local step at r=0 (multiple of 32)

    if (isProd && sb >= KCH) {             // head export: window [sb-127, sb-64]
      int ec = sb - 127 + lane;
      ec = ec < 0 ? 0 : (ec > LL ? LL : ec);
      __hip_atomic_store((int*)(glnk + ec), __float_as_int(bndX[8][ec + BOFF]),
                         __ATOMIC_RELAXED, __HIP_MEMORY_SCOPE_AGENT);
    }

    if (sb >= 0 && sb <= SBMAX) {
      // boundary window for THIS chunk (staged by neighbor in previous iteration)
      float B;
      if (isCons) {
        if (sb == 0) {
          pcurB = (int*)(glnk + lane);
          Bpre = __int_as_float(__hip_atomic_load(pcurB, __ATOMIC_RELAXED,
                                                  __HIP_MEMORY_SCOPE_AGENT));
        }
        float bv = Bpre;
        if (isL0 && sb == 0) bv = 0.f;                 // col 0 border: e = 0
        while (__ballot(bv < 0.f) & 0xffffffffull) {   // lanes 0..31 must be valid
          __builtin_amdgcn_s_sleep(2);
          bv = __int_as_float(__hip_atomic_load(pcurB, __ATOMIC_RELAXED,
                                                __HIP_MEMORY_SCOPE_AGENT));
          if (isL0 && sb == 0) bv = 0.f;
        }
        B = bv;
      } else {
        int colp = sb + lane; colp = colp > LL ? LL : colp;
        B = bndX[wprev][colp + BOFF];
      }

      const int base0 = loff + 8 * sb;
      LD4(Av0, Av1, Av2, Av3, base0);                 // g0: entries 0..7

      // staging: lane 63 -> boundary row (col sb+r-63 at index sb+1+r), else sink
      float* wbase = (lane == 63) ? &bndX[wwr][sb + 1] : &dumpA[wvs][lane];

      STEP(0); STEP(1); STEP(2);
      LD4(Bv0, Bv1, Bv2, Bv3, base0 + 64);            // g1: entries 8..15 (use r=8)
      STEP(3); STEP(4); STEP(5); STEP(6); STEP(7); STEP(8); STEP(9);
      LD4(Av0, Av1, Av2, Av3, base0 + 128);           // g2: entries 16..23 (use r=16)
      STEP(10); STEP(11); STEP(12); STEP(13); STEP(14); STEP(15); STEP(16); STEP(17);
      LD4(Bv0, Bv1, Bv2, Bv3, base0 + 192);           // g3: entries 24..31 (use r=24)
      STEP(18); STEP(19); STEP(20); STEP(21); STEP(22); STEP(23);
      STEP(24); STEP(25); STEP(26); STEP(27); STEP(28); STEP(29); STEP(30); STEP(31);

      if (isCons && sb + KCH <= SBMAX) {              // prefetch next boundary window
        int cn = sb + KCH + lane; cn = cn > LL ? LL : cn;
        pcurB = (int*)(glnk + cn);
        Bpre = __int_as_float(__hip_atomic_load(pcurB, __ATOMIC_RELAXED,
                                                __HIP_MEMORY_SCOPE_AGENT));
      }
    }
    __syncthreads();
  }

  if (isProd) {   // backstop: full boundary-row sweep (guarantees every col)
    for (int c0 = lane; c0 <= LL; c0 += 64)
      __hip_atomic_store((int*)(glnk + c0), __float_as_int(bndX[8][c0 + BOFF]),
                         __ATOMIC_RELAXED, __HIP_MEMORY_SCOPE_AGENT);
  }

  // final cell (1024,1024): WG1 wave 7 lane 63 at s = 1087 (chunk sb=1056, r=31)
  if (wg == 1 && t == NT - 1) wsf[bb] = costL + CLOG * __builtin_amdgcn_logf(lastmm);
}

__global__ void reduce_mean(const float* __restrict__ ws, float* __restrict__ out) {
  if (threadIdx.x == 0 && blockIdx.x == 0) {
    float s = 0.f;
    for (int i = 0; i < NB; ++i) s += ws[i];
    out[0] = s * (1.0f / NB);
  }
}

extern "C" void kernel_launch(void* const* d_in, const int* in_sizes, int n_in,
                              void* d_out, int out_size, void* d_ws, size_t ws_size,
                              hipStream_t stream) {
  const float* o  = (const float*)d_in[0];
  const float* tg = (const float*)d_in[1];
  float* ws  = (float*)d_ws;
  float* out = (float*)d_out;

  dtw_kernel<<<2 * NB, NT, 0, stream>>>(o, tg, ws);
  reduce_mean<<<1, 64, 0, stream>>>(ws, out);
}

// Round 13
// 108.307 us; speedup vs baseline: 1.0994x; 1.0168x over previous
//
#include <hip/hip_runtime.h>

#define LL    1024
#define NB    8
#define NT    256          // 4 waves per WG
#define KCH   64           // steps per chunk (one barrier per chunk)
#define SKEW  192          // intra-WG wave skew = 128 rows + KCH
#define SBMAX 1088         // last chunk start (covers local steps up to 1151)
#define NCH   27           // wave 3 last active chunk: (1088+576)/64 = 26
#define YTN   1280         // y-table entries (float2); index = j + 128
#define BROW  1160         // bndX row stride (floats)
#define BOFF  128          // col 0 of a boundary row at index BOFF
#define GBASE 64           // d_ws float offset of link regions
#define GSTR  1160         // per-batch link region stride (floats; 1025 used)
#define C10   14.426950408889634f        // 10*log2(e)
#define CLOG  (-0.069314718055994531f)   // -(ln2)/10
#define EPS3  1e-12f

// Soft-DTW in e-space (e = exp(-10*D)); 8 strips x 128 rows, 2 WGs x 4 waves.
// R13: R6-proven R=2 rows/lane core (lane l owns strip rows 2l, 2l+1) +
// R7's wave_shr:1 DPP & readlane-B + KCH=64 (2x overhead amortization) +
// ONE inter-WG LLC link per batch (R12-proven protocol).

// y-stream: entry for row a at step r has in-chunk index k=r; row b uses k=r-1.
// Group g covers k in [8g, 8g+7]; buffers alternate Av (g even), Bv (g odd).
// k=-1 reads the PREVIOUS chunk's g7 leftover in Bv (loaded last, retained).
#define YB4(k) ((((k) >> 3) & 1)                                               \
    ? (((((k) & 7) >> 1) == 0) ? Bv0 : ((((k) & 7) >> 1) == 1) ? Bv1           \
                               : ((((k) & 7) >> 1) == 2) ? Bv2 : Bv3)          \
    : (((((k) & 7) >> 1) == 0) ? Av0 : ((((k) & 7) >> 1) == 1) ? Av1           \
                               : ((((k) & 7) >> 1) == 2) ? Av2 : Av3))
#define FPE(k) (((k) & 1) ? YB4(k).z : YB4(k).x)
#define FNE(k) (((k) & 1) ? YB4(k).w : YB4(k).y)

// Strip-local rows: a = 2*lane, b = 2*lane+1. Cell (rr, j) at local step s=rr+j.
// All reads use PRE-step state; commits at the end (R6-proven ordering).
#define STEP(r) do {                                                           \
    const float fpa_ = FPE(r),       fna_ = FNE(r);                            \
    const float fpb_ = FPE((r) - 1), fnb_ = FNE((r) - 1);                      \
    const float dppv_ = __int_as_float(__builtin_amdgcn_update_dpp(            \
        0, __float_as_int(E1b), 0x138, 0xf, 0xf, true)); /* wave_shr:1 */      \
    const float bvs_ = __int_as_float(                                         \
        __builtin_amdgcn_readlane(__float_as_int(B), (r)));                    \
    const float upa_ = isL0 ? bvs_ : dppv_;                                    \
    const float eca_ = fminf(EN0 * fpa_, EP0 * fna_);                          \
    const float ecb_ = fminf(EN1 * fpb_, EP1 * fnb_);                          \
    const float mma_ = fmaf(up_del + E1a + upa_, (1.f / 3.f), EPS3);           \
    const float mmb_ = fmaf(E2a + E1b + E1a, (1.f / 3.f), EPS3);               \
    const float nva_ = eca_ * mma_;                                            \
    const float nvb_ = ecb_ * mmb_;                                            \
    wbase[(r)] = nvb_;                                                         \
    E2a = E1a; E1a = nva_; E1b = nvb_;                                         \
    up_del = upa_; lastmm = mmb_;                                              \
  } while (0)

#define LD4(d0, d1, d2, d3, byteoff) do {                                      \
    const char* p_ = (const char*)ytab + (byteoff);                            \
    d0 = *(const float4*)(p_);                                                 \
    d1 = *(const float4*)(p_ + 16);                                            \
    d2 = *(const float4*)(p_ + 32);                                            \
    d3 = *(const float4*)(p_ + 48);                                            \
  } while (0)

__global__ __launch_bounds__(NT, 1) void dtw_kernel(const float* __restrict__ outp,
                                                    const float* __restrict__ tgtp,
                                                    float* __restrict__ wsf) {
  const int bb = blockIdx.x & 7;       // batch (WG pair 8 blocks apart)
  const int wg = blockIdx.x >> 3;      // 0 = rows 1..512, 1 = rows 513..1024
  const int t = threadIdx.x;
  const int lane = t & 63;
  const int wvs = __builtin_amdgcn_readfirstlane(t >> 6);

  __shared__ float2 ytab[YTN];        // (fp,fn) at index j+128, zero guards
  __shared__ float  bndX[5][BROW];    // 0-2: waves 0-2 staging; 3: zeros+seed; 4: wave-3 staging
  __shared__ float  dumpA[4][64];     // LDS sink for non-lane-63 staging writes

  {
    float4* za = (float4*)&ytab[0];
    for (int i = t; i < (YTN * 2) / 4; i += NT) za[i] = make_float4(0.f, 0.f, 0.f, 0.f);
    float4* zb = (float4*)&bndX[0][0];
    for (int i = t; i < (5 * BROW) / 4; i += NT) zb[i] = make_float4(0.f, 0.f, 0.f, 0.f);
  }
  __syncthreads();

  const float* xb = outp + (size_t)bb * LL * LL;
  const float* yb = tgtp + (size_t)bb * LL * LL;

  // my rows: global rows 512*wg + 128*wvs + 2*lane + {1,2}
  const float2 xv = *(const float2*)(xb + 512 * wg + 128 * wvs + 2 * lane);
  const float EP0 = __builtin_amdgcn_exp2f( C10 * xv.x), EN0 = __builtin_amdgcn_exp2f(-C10 * xv.x);
  const float EP1 = __builtin_amdgcn_exp2f( C10 * xv.y), EN1 = __builtin_amdgcn_exp2f(-C10 * xv.y);

  {
    const float4 yv = *(const float4*)(yb + 4 * t);
    const float yy[4] = {yv.x, yv.y, yv.z, yv.w};
#pragma unroll
    for (int q = 0; q < 4; ++q) {
      const int j = 4 * t + 1 + q;                   // j in [1,1024]
      ytab[j + 128] = make_float2(__builtin_amdgcn_exp2f( C10 * yy[q]),
                                  __builtin_amdgcn_exp2f(-C10 * yy[q]));
    }
  }
  if (wg == 0 && t == 0) bndX[3][BOFF] = 1.0f;      // e[0,0] = 1 seed
  const float costL = (wg == 1 && t == NT - 1) ? fabsf(xv.y - yb[LL - 1]) : 0.f;
  __syncthreads();

  float E1a = 0.f, E1b = 0.f, E2a = 0.f;
  float up_del = 0.f, lastmm = EPS3;
  float4 Av0, Av1, Av2, Av3;
  float4 Bv0 = make_float4(0.f, 0.f, 0.f, 0.f), Bv1 = Bv0, Bv2 = Bv0, Bv3 = Bv0;
  Av0 = Bv0; Av1 = Bv0; Av2 = Bv0; Av3 = Bv0;
  const bool isL0 = (lane == 0);
  const int wprev = (wvs == 0) ? 3 : (wvs - 1);
  const int wwr   = (wvs == 3) ? 4 : wvs;
  const bool isProd = (wg == 0) && (wvs == 3);
  const bool isCons = (wg == 1) && (wvs == 0);
  const int loff = 8 * (128 - 2 * lane);             // byte base at sb=0 (16B-aligned)

  float* glnk = wsf + GBASE + bb * GSTR;             // link cols 0..1024

  float Bpre = 0.f;
  int*  pcurB = (int*)glnk;
  if (isCons) {
    // sentinel-fill our link region (robust to any initial / stale d_ws content)
    for (int c0 = lane; c0 <= LL; c0 += 64)
      __hip_atomic_store((int*)(glnk + c0), __float_as_int(-1.0f),
                         __ATOMIC_RELAXED, __HIP_MEMORY_SCOPE_AGENT);
    __threadfence();
  }

#pragma unroll 1
  for (int c = 0; c < NCH; ++c) {
    const int sb = KCH * c - SKEW * wvs;   // local step at r=0 (multiple of 64)

    if (isProd && sb >= KCH) {             // head export: cols [sb-191, sb-128]
      int ec = sb - 191 + lane;
      ec = ec < 0 ? 0 : (ec > LL ? LL : ec);
      __hip_atomic_store((int*)(glnk + ec), __float_as_int(bndX[4][ec + BOFF]),
                         __ATOMIC_RELAXED, __HIP_MEMORY_SCOPE_AGENT);
    }

    if (sb >= 0 && sb <= SBMAX) {
      // boundary window for THIS chunk: B[lane] = up-row value at col sb+lane
      float B;
      if (isCons) {
        if (sb == 0) {
          pcurB = (int*)(glnk + lane);
          Bpre = __int_as_float(__hip_atomic_load(pcurB, __ATOMIC_RELAXED,
                                                  __HIP_MEMORY_SCOPE_AGENT));
        }
        float bv = Bpre;
        if (isL0 && sb == 0) bv = 0.f;                 // col 0 border: e = 0
        while (__ballot(bv < 0.f)) {                   // all 64 lanes must be valid
          __builtin_amdgcn_s_sleep(2);
          bv = __int_as_float(__hip_atomic_load(pcurB, __ATOMIC_RELAXED,
                                                __HIP_MEMORY_SCOPE_AGENT));
          if (isL0 && sb == 0) bv = 0.f;
        }
        B = bv;
      } else {
        int colp = sb + lane; colp = colp > LL ? LL : colp;
        B = bndX[wprev][colp + BOFF];
      }

      const int base0 = loff + 8 * sb;
      LD4(Av0, Av1, Av2, Av3, base0);                 // g0 (k 0..7); used r=0
      // staging: lane 63 row b -> boundary row (col sb+r-127 at idx sb+1+r), else sink
      float* wbase = (lane == 63) ? &bndX[wwr][sb + 1] : &dumpA[wvs][lane];

      STEP(0); STEP(1);
      LD4(Bv0, Bv1, Bv2, Bv3, base0 + 64);            // g1 (k 8..15);  used r=8
      STEP(2); STEP(3); STEP(4); STEP(5); STEP(6); STEP(7); STEP(8);
      LD4(Av0, Av1, Av2, Av3, base0 + 128);           // g2 (k 16..23); used r=16
      STEP(9); STEP(10); STEP(11); STEP(12); STEP(13); STEP(14); STEP(15); STEP(16);
      LD4(Bv0, Bv1, Bv2, Bv3, base0 + 192);           // g3 (k 24..31); used r=24
      STEP(17); STEP(18); STEP(19); STEP(20); STEP(21); STEP(22); STEP(23); STEP(24);
      LD4(Av0, Av1, Av2, Av3, base0 + 256);           // g4 (k 32..39); used r=32
      STEP(25); STEP(26); STEP(27); STEP(28); STEP(29); STEP(30); STEP(31); STEP(32);
      LD4(Bv0, Bv1, Bv2, Bv3, base0 + 320);           // g5 (k 40..47); used r=40
      STEP(33); STEP(34); STEP(35); STEP(36); STEP(37); STEP(38); STEP(39); STEP(40);
      LD4(Av0, Av1, Av2, Av3, base0 + 384);           // g6 (k 48..55); used r=48
      STEP(41); STEP(42); STEP(43); STEP(44); STEP(45); STEP(46); STEP(47); STEP(48);
      LD4(Bv0, Bv1, Bv2, Bv3, base0 + 448);           // g7 (k 56..63); used r=56,
      STEP(49); STEP(50); STEP(51); STEP(52);         //   retained for next r=0 (k=-1)
      STEP(53); STEP(54); STEP(55); STEP(56); STEP(57); STEP(58); STEP(59);
      STEP(60); STEP(61); STEP(62); STEP(63);

      if (isCons && sb + KCH <= SBMAX) {              // prefetch next boundary window
        int cn = sb + KCH + lane; cn = cn > LL ? LL : cn;
        pcurB = (int*)(glnk + cn);
        Bpre = __int_as_float(__hip_atomic_load(pcurB, __ATOMIC_RELAXED,
                                                __HIP_MEMORY_SCOPE_AGENT));
      }
    }
    __syncthreads();
  }

  if (isProd) {   // backstop: full boundary-row sweep (guarantees final cols)
    for (int c0 = lane; c0 <= LL; c0 += 64)
      __hip_atomic_store((int*)(glnk + c0), __float_as_int(bndX[4][c0 + BOFF]),
                         __ATOMIC_RELAXED, __HIP_MEMORY_SCOPE_AGENT);
  }

  // final cell (1024,1024): WG1 wave 3 lane 63 row b at s=1151 (sb=1088, r=63)
  if (wg == 1 && t == NT - 1) wsf[bb] = costL + CLOG * __builtin_amdgcn_logf(lastmm);
}

__global__ void reduce_mean(const float* __restrict__ ws, float* __restrict__ out) {
  if (threadIdx.x == 0 && blockIdx.x == 0) {
    float s = 0.f;
    for (int i = 0; i < NB; ++i) s += ws[i];
    out[0] = s * (1.0f / NB);
  }
}

extern "C" void kernel_launch(void* const* d_in, const int* in_sizes, int n_in,
                              void* d_out, int out_size, void* d_ws, size_t ws_size,
                              hipStream_t stream) {
  const float* o  = (const float*)d_in[0];
  const float* tg = (const float*)d_in[1];
  float* ws  = (float*)d_ws;
  float* out = (float*)d_out;

  dtw_kernel<<<2 * NB, NT, 0, stream>>>(o, tg, ws);
  reduce_mean<<<1, 64, 0, stream>>>(ws, out);
}

// Round 14
// 90.488 us; speedup vs baseline: 1.3158x; 1.1969x over previous
//
#include <hip/hip_runtime.h>

#define LL    1024
#define NB    8
#define NT    256          // 4 waves per WG
#define KCH   32           // steps per chunk (one barrier per chunk)
#define SKEW  96           // intra-WG wave skew = 64 rows + KCH
#define SMAX  1087         // last local step (lane 63: 63 + 1024)
#define NCH   43           // wave 3 last active chunk: (1056+288)/32 = 42
#define YTN   1536         // y-table entries (float2)
#define BROW  1160         // bndX row stride (floats)
#define BOFF  128          // col 0 of a boundary row at index BOFF
#define GBASE 64           // d_ws float offset of link regions
#define GSTR  1280         // per-link region stride (floats)
#define C10   14.426950408889634f        // 10*log2(e)
#define CLOG  (-0.069314718055994531f)   // -(ln2)/10
#define EPS3  1e-12f

// Soft-DTW in e-space (e = exp(-10*D)); 16 strips x 64 rows across 4 WGs/batch.
// R14 = R7 verbatim (best measured, 92.5us bench / 87.5us dispatch) + ONLY:
//  (a) cross-barrier LD4 double-buffering: next chunk's g0/g1 loaded at current
//      chunk tail (buffers dead after r=23/r=31); barrier drain completes them.
//  (b) NCH 45 -> 43 (trim two all-idle barrier iterations).

#define YB4(k) ((((k) >> 3) & 1)                                               \
    ? (((((k) & 7) >> 1) == 0) ? Bv0 : ((((k) & 7) >> 1) == 1) ? Bv1           \
                               : ((((k) & 7) >> 1) == 2) ? Bv2 : Bv3)          \
    : (((((k) & 7) >> 1) == 0) ? Av0 : ((((k) & 7) >> 1) == 1) ? Av1           \
                               : ((((k) & 7) >> 1) == 2) ? Av2 : Av3))
#define FPE(k) (((k) & 1) ? YB4(k).z : YB4(k).x)
#define FNE(k) (((k) & 1) ? YB4(k).w : YB4(k).y)

// Cell (lane+1, j) at local step s = lane + j; entry ji = s - lane + 256.
#define STEP(r) do {                                                           \
    const float fp_ = FPE(r);                                                  \
    const float fn_ = FNE(r);                                                  \
    const float dppv_ = __int_as_float(__builtin_amdgcn_update_dpp(            \
        0, __float_as_int(E1), 0x138, 0xf, 0xf, true)); /* wave_shr:1 */       \
    const float bvs_ = __int_as_float(                                         \
        __builtin_amdgcn_readlane(__float_as_int(B), (r)));                    \
    const float upa_ = isL0 ? bvs_ : dppv_;                                    \
    const float eca_ = fminf(EN0 * fp_, EP0 * fn_);                            \
    const float mma_ = fmaf(up_del + E1 + upa_, (1.f / 3.f), EPS3);            \
    const float nva_ = eca_ * mma_;                                            \
    wbase[(r)] = nva_;                                                         \
    E1 = nva_; up_del = upa_; lastmm = mma_;                                   \
  } while (0)

#define LD4(d0, d1, d2, d3, byteoff) do {                                      \
    const char* p_ = ytp + (byteoff);                                          \
    d0 = *(const float4*)(p_);                                                 \
    d1 = *(const float4*)(p_ + 16);                                            \
    d2 = *(const float4*)(p_ + 32);                                            \
    d3 = *(const float4*)(p_ + 48);                                            \
  } while (0)

__global__ __launch_bounds__(NT, 1) void dtw_kernel(const float* __restrict__ outp,
                                                    const float* __restrict__ tgtp,
                                                    float* __restrict__ wsf) {
  const int bb = blockIdx.x >> 2;      // batch
  const int wg = blockIdx.x & 3;       // quarter: rows 256*wg+1 .. 256*wg+256
  const int t = threadIdx.x;
  const int lane = t & 63;
  const int wvs = __builtin_amdgcn_readfirstlane(t >> 6);

  __shared__ float2 ytabA[YTN];       // (fp,fn) at slot ji        (even lanes)
  __shared__ float2 ytabB[YTN];       // (fp,fn) at slot ji - 1    (odd lanes)
  __shared__ float  bndX[5][BROW];    // 0-2: waves 0-2 boundaries; 3: zeros+seed; 4: wave-3 staging
  __shared__ float  dumpA[4][128];    // LDS sink for non-lane-63 staging writes

  {
    float4* za = (float4*)&ytabA[0];
    for (int i = t; i < (YTN * 2) / 4; i += NT) za[i] = make_float4(0.f, 0.f, 0.f, 0.f);
    float4* zb2 = (float4*)&ytabB[0];
    for (int i = t; i < (YTN * 2) / 4; i += NT) zb2[i] = make_float4(0.f, 0.f, 0.f, 0.f);
    float4* zb = (float4*)&bndX[0][0];
    for (int i = t; i < (5 * BROW) / 4; i += NT) zb[i] = make_float4(0.f, 0.f, 0.f, 0.f);
  }
  __syncthreads();

  const float* xb = outp + (size_t)bb * LL * LL;
  const float* yb = tgtp + (size_t)bb * LL * LL;

  // my row: global row 256*wg + 64*wvs + lane + 1
  const float xd = xb[256 * wg + 64 * wvs + lane];
  const float EP0 = __builtin_amdgcn_exp2f( C10 * xd);
  const float EN0 = __builtin_amdgcn_exp2f(-C10 * xd);

  {
    const float4 yv = *(const float4*)(yb + 4 * t);
    const float yy[4] = {yv.x, yv.y, yv.z, yv.w};
#pragma unroll
    for (int q = 0; q < 4; ++q) {
      const int ji = (4 * t + 1 + q) + 256;          // j in [1,1024]
      const float2 v = make_float2(__builtin_amdgcn_exp2f( C10 * yy[q]),
                                   __builtin_amdgcn_exp2f(-C10 * yy[q]));
      ytabA[ji] = v;
      ytabB[ji - 1] = v;
    }
  }
  if (wg == 0 && t == 0) bndX[3][BOFF] = 1.0f;      // e[0,0] = 1 seed
  const float costL = (wg == 3 && t == NT - 1) ? fabsf(xd - yb[LL - 1]) : 0.f;
  __syncthreads();

  float E1 = 0.f, up_del = 0.f, lastmm = EPS3;
  float4 Av0, Av1, Av2, Av3;
  float4 Bv0 = make_float4(0.f, 0.f, 0.f, 0.f), Bv1 = Bv0, Bv2 = Bv0, Bv3 = Bv0;
  Av0 = Bv0; Av1 = Bv0; Av2 = Bv0; Av3 = Bv0;
  const bool isL0 = (lane == 0);
  const int wprev = (wvs == 0) ? 3 : (wvs - 1);
  const int wwr   = (wvs == 3) ? 4 : wvs;
  const bool isProd = (wg < 3) && (wvs == 3);
  const bool isCons = (wg > 0) && (wvs == 0);
  // per-lane y-table view: 16B-aligned for every lane via the dual table
  const char* ytp = (lane & 1) ? (const char*)ytabB : (const char*)ytabA;
  const int   loff = 8 * (((lane & 1) ? 255 : 256) - lane);

  float* gprod = wsf + GBASE + (bb * 3 + wg)     * GSTR + 128;  // valid when wg<3
  float* gcons = wsf + GBASE + (bb * 3 + wg - 1) * GSTR + 128;  // valid when wg>0

  float Bnext = 0.f;
  int*  pcur  = (int*)gcons;
  if (isCons) {
    // sentinel-fill our link region (robust to any initial / stale d_ws content)
    for (int c0 = lane; c0 <= LL; c0 += 64)
      __hip_atomic_store((int*)(gcons + c0), __float_as_int(-1.0f),
                         __ATOMIC_RELAXED, __HIP_MEMORY_SCOPE_AGENT);
    __threadfence();
    pcur = (int*)(gcons + lane);
    Bnext = __int_as_float(__hip_atomic_load(pcur, __ATOMIC_RELAXED, __HIP_MEMORY_SCOPE_AGENT));
  }

#pragma unroll 1
  for (int c = 0; c < NCH; ++c) {
    const int sb = KCH * c - SKEW * wvs;   // local step at r=0 (multiple of 32)

    if (isProd && sb >= 64) {              // head export: window [sb-127, sb-64]
      int ec = sb - 127 + lane;
      ec = ec < 0 ? 0 : (ec > LL ? LL : ec);
      const float ev = bndX[4][ec + BOFF];
      __hip_atomic_store((int*)(gprod + ec), __float_as_int(ev),
                         __ATOMIC_RELAXED, __HIP_MEMORY_SCOPE_AGENT);
    }

    if (sb >= 0 && sb <= SMAX - (KCH - 1)) {
      // boundary preload: lane l holds up-value for step sb+l (col sb+l); r<32 used
      float B;
      if (isCons) {
        float bv = Bnext;
        for (int tries = 0;
             (__ballot(bv < 0.f) & 0xffffffffull) && tries < (1 << 16); ++tries) {
          __builtin_amdgcn_s_sleep(2);
          bv = __int_as_float(__hip_atomic_load(pcur, __ATOMIC_RELAXED, __HIP_MEMORY_SCOPE_AGENT));
        }
        B = bv;
        int cn = sb + KCH + lane; cn = cn > LL ? LL : cn;       // prefetch next chunk
        pcur = (int*)(gcons + cn);
        Bnext = __int_as_float(__hip_atomic_load(pcur, __ATOMIC_RELAXED, __HIP_MEMORY_SCOPE_AGENT));
      } else {
        int colp = sb + lane; colp = colp > LL ? LL : colp;
        B = bndX[wprev][colp + BOFF];
      }

      const int base0 = loff + 8 * sb;
      if (sb == 0) {                       // first active chunk: no prefetch cover
        LD4(Av0, Av1, Av2, Av3, base0);             // g0: entries 0..7
        LD4(Bv0, Bv1, Bv2, Bv3, base0 + 64);        // g1: entries 8..15
      }

      // staging: lane 63 -> boundary row (col sb+r-63 at index sb+65+r), else sink
      float* wbase = (lane == 63) ? &bndX[wwr][sb + 65] : &dumpA[wvs][lane];

      STEP(0); STEP(1); STEP(2); STEP(3); STEP(4); STEP(5); STEP(6); STEP(7);
      LD4(Av0, Av1, Av2, Av3, base0 + 128);         // g2: entries 16..23 (use r=16)
      STEP(8); STEP(9); STEP(10); STEP(11); STEP(12); STEP(13); STEP(14); STEP(15);
      LD4(Bv0, Bv1, Bv2, Bv3, base0 + 192);         // g3: entries 24..31 (use r=24)
      STEP(16); STEP(17); STEP(18); STEP(19); STEP(20); STEP(21); STEP(22); STEP(23);
      const bool nact = (sb + KCH <= SMAX - (KCH - 1));
      if (nact) LD4(Av0, Av1, Av2, Av3, base0 + 256);   // next g0 (Av dead after r=23)
      STEP(24); STEP(25); STEP(26); STEP(27); STEP(28); STEP(29); STEP(30); STEP(31);
      if (nact) LD4(Bv0, Bv1, Bv2, Bv3, base0 + 320);   // next g1 (Bv dead after r=31)
    }
    __syncthreads();
  }

  if (isProd) {   // backstop: full boundary-row sweep (guarantees every col)
    for (int c0 = lane; c0 <= LL; c0 += 64)
      __hip_atomic_store((int*)(gprod + c0), __float_as_int(bndX[4][c0 + BOFF]),
                         __ATOMIC_RELAXED, __HIP_MEMORY_SCOPE_AGENT);
  }

  // final cell (1024,1024): WG3 wave 3 lane 63 at s = 1087 (chunk sb=1056, r=31)
  if (wg == 3 && t == NT - 1) wsf[bb] = costL + CLOG * __builtin_amdgcn_logf(lastmm);
}

__global__ void reduce_mean(const float* __restrict__ ws, float* __restrict__ out) {
  if (threadIdx.x == 0 && blockIdx.x == 0) {
    float s = 0.f;
    for (int i = 0; i < NB; ++i) s += ws[i];
    out[0] = s * (1.0f / NB);
  }
}

extern "C" void kernel_launch(void* const* d_in, const int* in_sizes, int n_in,
                              void* d_out, int out_size, void* d_ws, size_t ws_size,
                              hipStream_t stream) {
  const float* o  = (const float*)d_in[0];
  const float* tg = (const float*)d_in[1];
  float* ws  = (float*)d_ws;
  float* out = (float*)d_out;

  dtw_kernel<<<4 * NB, NT, 0, stream>>>(o, tg, ws);
  reduce_mean<<<1, 64, 0, stream>>>(ws, out);
}